// Round 1
// baseline (276.433 us; speedup 1.0000x reference)
//
#include <hip/hip_runtime.h>

#define LOG64f 4.1588830833596715f
#define LOG32f 3.4657359027997265f
#define LOG16f 2.7725887222397810f

// One 64-lane wave processes 4 consecutive fragments.
// Track 0 (S=64): 4 passes, full-wave row.
// Track 1 (S=32): 2 passes, two 32-lane segments (2 rows/pass).
// Track 2 (S=16): 1 pass, four 16-lane segments (4 rows/pass).
// All bincount loads are contiguous 256B per wave instruction (coalesced).

__global__ __launch_bounds__(256) void frag_pos_dist_kernel(
    const int* __restrict__ bc0, const int* __restrict__ bc1, const int* __restrict__ bc2,
    const int* __restrict__ gix, const int* __restrict__ bix,
    const int* __restrict__ labels, const int* __restrict__ lci,
    const float* __restrict__ bw0, const float* __restrict__ d0,
    const float* __restrict__ bw1, const float* __restrict__ d1,
    const float* __restrict__ bw2, const float* __restrict__ d2,
    float* __restrict__ out, int N)
{
    const int tid  = blockIdx.x * blockDim.x + threadIdx.x;
    const int wave = tid >> 6;
    const int lane = threadIdx.x & 63;
    const int base = wave * 4;
    if (base >= N) return;

    // ---- per-fragment scalars: lane l holds scalars for fragment base+(l&3) ----
    float dv0, dv1, dv2;
    int g0, g1, g2, b0, b1, b2;
    {
        int n = base + (lane & 3);
        if (n >= N) n = N - 1;
        const int cell = lci[n];
        const int lab  = labels[cell];
        dv0 = d0[lab]; dv1 = d1[lab]; dv2 = d2[lab];
        g0 = gix[n * 3 + 0]; g1 = gix[n * 3 + 1]; g2 = gix[n * 3 + 2];
        b0 = bix[n * 3 + 0]; b1 = bix[n * 3 + 1]; b2 = bix[n * 3 + 2];
    }

    float acc = 0.0f;

    // ---------------- track 0: S = 64 ----------------
    #pragma unroll
    for (int f = 0; f < 4; ++f) {
        int n = base + f; if (n >= N) n = N - 1;
        const float dv = __shfl(dv0, f);
        const int   g  = __shfl(g0, f);
        const int   b  = __shfl(b0, f);
        const int   c  = bc0[n * 64 + lane];
        const float u  = (c > 1 ? dv : 0.0f) + bw0[g * 64 + lane];
        float m = u;
        #pragma unroll
        for (int off = 32; off; off >>= 1) m = fmaxf(m, __shfl_xor(m, off));
        float e = __expf(u - m);
        #pragma unroll
        for (int off = 32; off; off >>= 1) e += __shfl_xor(e, off);
        const float ub = __shfl(u, b);
        const float lp = ub - m - __logf(e) + LOG64f;
        if (lane == f) acc += lp;
    }

    // ---------------- track 1: S = 32 ----------------
    #pragma unroll
    for (int p = 0; p < 2; ++p) {
        const int h = lane >> 5;              // which 32-lane segment
        const int f = p * 2 + h;              // fragment offset handled by this segment
        int n = base + f; if (n >= N) n = N - 1;
        const float dv = __shfl(dv1, f);
        const int   g  = __shfl(g1, f);
        const int   b  = __shfl(b1, f);
        const int   c  = bc1[n * 32 + (lane & 31)];
        const float u  = (c > 1 ? dv : 0.0f) + bw1[g * 32 + (lane & 31)];
        float m = u;
        #pragma unroll
        for (int off = 16; off; off >>= 1) m = fmaxf(m, __shfl_xor(m, off));
        float e = __expf(u - m);
        #pragma unroll
        for (int off = 16; off; off >>= 1) e += __shfl_xor(e, off);
        const float ub = __shfl(u, h * 32 + b);
        const float lp = ub - m - __logf(e) + LOG32f;
        // fragment p*2 result lives in lanes [0,32), p*2+1 in [32,64)
        const float t = __shfl(lp, (lane & 1) * 32);
        if ((lane >> 1) == p && lane < 4) acc += t;
    }

    // ---------------- track 2: S = 16 ----------------
    {
        const int q = lane >> 4;              // which 16-lane segment
        int n = base + q; if (n >= N) n = N - 1;
        const float dv = __shfl(dv2, q);
        const int   g  = __shfl(g2, q);
        const int   b  = __shfl(b2, q);
        const int   c  = bc2[n * 16 + (lane & 15)];
        const float u  = (c > 1 ? dv : 0.0f) + bw2[g * 16 + (lane & 15)];
        float m = u;
        #pragma unroll
        for (int off = 8; off; off >>= 1) m = fmaxf(m, __shfl_xor(m, off));
        float e = __expf(u - m);
        #pragma unroll
        for (int off = 8; off; off >>= 1) e += __shfl_xor(e, off);
        const float ub = __shfl(u, q * 16 + b);
        const float lp = ub - m - __logf(e) + LOG16f;
        const float t = __shfl(lp, (lane & 3) * 16);
        if (lane < 4) acc += t;
    }

    // ---------------- write: lanes 0..3 own fragments base..base+3 ----------------
    if (lane < 4) {
        const int n = base + lane;
        if (n < N) out[n] = acc;
    }
}

extern "C" void kernel_launch(void* const* d_in, const int* in_sizes, int n_in,
                              void* d_out, int out_size, void* d_ws, size_t ws_size,
                              hipStream_t stream) {
    const int* bc0    = (const int*)d_in[0];
    const int* bc1    = (const int*)d_in[1];
    const int* bc2    = (const int*)d_in[2];
    const int* gix    = (const int*)d_in[3];
    const int* bixp   = (const int*)d_in[4];
    const int* labels = (const int*)d_in[5];
    const int* lci    = (const int*)d_in[6];
    const float* bw0  = (const float*)d_in[7];
    const float* dv0  = (const float*)d_in[8];
    const float* bw1  = (const float*)d_in[9];
    const float* dv1  = (const float*)d_in[10];
    const float* bw2  = (const float*)d_in[11];
    const float* dv2  = (const float*)d_in[12];
    float* out = (float*)d_out;

    const int N = in_sizes[6];  // local_cell_ix has N elements
    const int threads = 256;
    const int fragsPerBlock = 16;       // 4 waves * 4 fragments
    const int blocks = (N + fragsPerBlock - 1) / fragsPerBlock;

    frag_pos_dist_kernel<<<blocks, threads, 0, stream>>>(
        bc0, bc1, bc2, gix, bixp, labels, lci,
        bw0, dv0, bw1, dv1, bw2, dv2, out, N);
}

// Round 2
// 234.414 us; speedup vs baseline: 1.1792x; 1.1792x over previous
//
#include <hip/hip_runtime.h>

#define LOG64f 4.1588830833596715f
#define LOG32f 3.4657359027997265f
#define LOG16f 2.7725887222397810f

// One thread per fragment. No cross-lane ops, no LDS.
// Per track: stream the row with int4/float4 loads, accumulate sum(exp(u))
// (no max pass -- u is bounded ~|10|, fp32 exp is safe), recompute u[b]
// from the (L1-hot) row directly.

__global__ __launch_bounds__(256) void frag_pos_dist_kernel(
    const int* __restrict__ bc0, const int* __restrict__ bc1, const int* __restrict__ bc2,
    const int* __restrict__ gix, const int* __restrict__ bix,
    const int* __restrict__ labels, const int* __restrict__ lci,
    const float* __restrict__ bw0, const float* __restrict__ d0,
    const float* __restrict__ bw1, const float* __restrict__ d1,
    const float* __restrict__ bw2, const float* __restrict__ d2,
    float* __restrict__ out, int N)
{
    const int n = blockIdx.x * blockDim.x + threadIdx.x;
    if (n >= N) return;

    const int cell = lci[n];
    const int lab  = labels[cell];

    const int g0 = gix[3 * n + 0], g1 = gix[3 * n + 1], g2 = gix[3 * n + 2];
    const int b0 = bix[3 * n + 0], b1 = bix[3 * n + 1], b2 = bix[3 * n + 2];

    float acc = 0.0f;

    // ---------------- track 0: S = 64 (16 x int4) ----------------
    {
        const float dv = d0[lab];
        const int4*   cv = (const int4*)(bc0 + (size_t)n * 64);
        const float4* wv = (const float4*)(bw0 + (size_t)g0 * 64);
        float s0 = 0.f, s1 = 0.f, s2 = 0.f, s3 = 0.f;
        #pragma unroll
        for (int k = 0; k < 16; ++k) {
            const int4   c = cv[k];
            const float4 w = wv[k];
            s0 += __expf((c.x > 1 ? dv : 0.f) + w.x);
            s1 += __expf((c.y > 1 ? dv : 0.f) + w.y);
            s2 += __expf((c.z > 1 ? dv : 0.f) + w.z);
            s3 += __expf((c.w > 1 ? dv : 0.f) + w.w);
        }
        const float ub = (bc0[(size_t)n * 64 + b0] > 1 ? dv : 0.f) + bw0[(size_t)g0 * 64 + b0];
        acc += ub - __logf((s0 + s1) + (s2 + s3)) + LOG64f;
    }

    // ---------------- track 1: S = 32 (8 x int4) ----------------
    {
        const float dv = d1[lab];
        const int4*   cv = (const int4*)(bc1 + (size_t)n * 32);
        const float4* wv = (const float4*)(bw1 + (size_t)g1 * 32);
        float s0 = 0.f, s1 = 0.f, s2 = 0.f, s3 = 0.f;
        #pragma unroll
        for (int k = 0; k < 8; ++k) {
            const int4   c = cv[k];
            const float4 w = wv[k];
            s0 += __expf((c.x > 1 ? dv : 0.f) + w.x);
            s1 += __expf((c.y > 1 ? dv : 0.f) + w.y);
            s2 += __expf((c.z > 1 ? dv : 0.f) + w.z);
            s3 += __expf((c.w > 1 ? dv : 0.f) + w.w);
        }
        const float ub = (bc1[(size_t)n * 32 + b1] > 1 ? dv : 0.f) + bw1[(size_t)g1 * 32 + b1];
        acc += ub - __logf((s0 + s1) + (s2 + s3)) + LOG32f;
    }

    // ---------------- track 2: S = 16 (4 x int4) ----------------
    {
        const float dv = d2[lab];
        const int4*   cv = (const int4*)(bc2 + (size_t)n * 16);
        const float4* wv = (const float4*)(bw2 + (size_t)g2 * 16);
        float s0 = 0.f, s1 = 0.f, s2 = 0.f, s3 = 0.f;
        #pragma unroll
        for (int k = 0; k < 4; ++k) {
            const int4   c = cv[k];
            const float4 w = wv[k];
            s0 += __expf((c.x > 1 ? dv : 0.f) + w.x);
            s1 += __expf((c.y > 1 ? dv : 0.f) + w.y);
            s2 += __expf((c.z > 1 ? dv : 0.f) + w.z);
            s3 += __expf((c.w > 1 ? dv : 0.f) + w.w);
        }
        const float ub = (bc2[(size_t)n * 16 + b2] > 1 ? dv : 0.f) + bw2[(size_t)g2 * 16 + b2];
        acc += ub - __logf((s0 + s1) + (s2 + s3)) + LOG16f;
    }

    out[n] = acc;
}

extern "C" void kernel_launch(void* const* d_in, const int* in_sizes, int n_in,
                              void* d_out, int out_size, void* d_ws, size_t ws_size,
                              hipStream_t stream) {
    const int* bc0    = (const int*)d_in[0];
    const int* bc1    = (const int*)d_in[1];
    const int* bc2    = (const int*)d_in[2];
    const int* gix    = (const int*)d_in[3];
    const int* bixp   = (const int*)d_in[4];
    const int* labels = (const int*)d_in[5];
    const int* lci    = (const int*)d_in[6];
    const float* bw0  = (const float*)d_in[7];
    const float* dv0  = (const float*)d_in[8];
    const float* bw1  = (const float*)d_in[9];
    const float* dv1  = (const float*)d_in[10];
    const float* bw2  = (const float*)d_in[11];
    const float* dv2  = (const float*)d_in[12];
    float* out = (float*)d_out;

    const int N = in_sizes[6];  // local_cell_ix has N elements
    const int threads = 256;
    const int blocks = (N + threads - 1) / threads;

    frag_pos_dist_kernel<<<blocks, threads, 0, stream>>>(
        bc0, bc1, bc2, gix, bixp, labels, lci,
        bw0, dv0, bw1, dv1, bw2, dv2, out, N);
}

// Round 3
// 134.161 us; speedup vs baseline: 2.0605x; 1.7473x over previous
//
#include <hip/hip_runtime.h>

#define LOG64f 4.1588830833596715f
#define LOG32f 3.4657359027997265f
#define LOG16f 2.7725887222397810f

// 4 lanes per fragment. Lane sub=tid&3 owns int4 chunks {sub, sub+4, ...} of
// the fragment's row, so each wave instruction reads 16 contiguous 64B
// sectors (full-sector transactions) instead of 64 scattered lines.
// Serial sum(exp(u)) per lane (u bounded ~|10| -> no max pass), then a
// 2-step shfl_xor reduce within the 4-lane group. No LDS, no barriers.

__global__ __launch_bounds__(256) void frag_pos_dist_kernel(
    const int* __restrict__ bc0, const int* __restrict__ bc1, const int* __restrict__ bc2,
    const int* __restrict__ gix, const int* __restrict__ bix,
    const int* __restrict__ labels, const int* __restrict__ lci,
    const float* __restrict__ bw0, const float* __restrict__ d0,
    const float* __restrict__ bw1, const float* __restrict__ d1,
    const float* __restrict__ bw2, const float* __restrict__ d2,
    float* __restrict__ out, int N)
{
    const int t   = blockIdx.x * blockDim.x + threadIdx.x;
    const int n   = t >> 2;          // fragment index
    const int sub = t & 3;           // position within the 4-lane group
    if (n >= N) return;

    const int cell = lci[n];
    const int lab  = labels[cell];
    const int g0 = gix[3 * n + 0], g1 = gix[3 * n + 1], g2 = gix[3 * n + 2];
    const int b0 = bix[3 * n + 0], b1 = bix[3 * n + 1], b2 = bix[3 * n + 2];

    float acc = 0.0f;

    // ---------------- track 0: S = 64 (4 chunks per lane) ----------------
    {
        const float dv = d0[lab];
        const int4*   cv = (const int4*)(bc0 + (size_t)n * 64);
        const float4* wv = (const float4*)(bw0 + (size_t)g0 * 64);
        float s = 0.f, ub = 0.f;
        #pragma unroll
        for (int k = 0; k < 4; ++k) {
            const int c4 = sub + 4 * k;
            const int4   c = cv[c4];
            const float4 w = wv[c4];
            const float u0 = (c.x > 1 ? dv : 0.f) + w.x;
            const float u1 = (c.y > 1 ? dv : 0.f) + w.y;
            const float u2 = (c.z > 1 ? dv : 0.f) + w.z;
            const float u3 = (c.w > 1 ? dv : 0.f) + w.w;
            s += (__expf(u0) + __expf(u1)) + (__expf(u2) + __expf(u3));
            if (c4 == (b0 >> 2)) {
                const int r = b0 & 3;
                ub = r == 0 ? u0 : r == 1 ? u1 : r == 2 ? u2 : u3;
            }
        }
        s  += __shfl_xor(s, 1);  s  += __shfl_xor(s, 2);
        ub += __shfl_xor(ub, 1); ub += __shfl_xor(ub, 2);
        acc += ub - __logf(s) + LOG64f;
    }

    // ---------------- track 1: S = 32 (2 chunks per lane) ----------------
    {
        const float dv = d1[lab];
        const int4*   cv = (const int4*)(bc1 + (size_t)n * 32);
        const float4* wv = (const float4*)(bw1 + (size_t)g1 * 32);
        float s = 0.f, ub = 0.f;
        #pragma unroll
        for (int k = 0; k < 2; ++k) {
            const int c4 = sub + 4 * k;
            const int4   c = cv[c4];
            const float4 w = wv[c4];
            const float u0 = (c.x > 1 ? dv : 0.f) + w.x;
            const float u1 = (c.y > 1 ? dv : 0.f) + w.y;
            const float u2 = (c.z > 1 ? dv : 0.f) + w.z;
            const float u3 = (c.w > 1 ? dv : 0.f) + w.w;
            s += (__expf(u0) + __expf(u1)) + (__expf(u2) + __expf(u3));
            if (c4 == (b1 >> 2)) {
                const int r = b1 & 3;
                ub = r == 0 ? u0 : r == 1 ? u1 : r == 2 ? u2 : u3;
            }
        }
        s  += __shfl_xor(s, 1);  s  += __shfl_xor(s, 2);
        ub += __shfl_xor(ub, 1); ub += __shfl_xor(ub, 2);
        acc += ub - __logf(s) + LOG32f;
    }

    // ---------------- track 2: S = 16 (1 chunk per lane) ----------------
    {
        const float dv = d2[lab];
        const int4   c = ((const int4*)(bc2 + (size_t)n * 16))[sub];
        const float4 w = ((const float4*)(bw2 + (size_t)g2 * 16))[sub];
        const float u0 = (c.x > 1 ? dv : 0.f) + w.x;
        const float u1 = (c.y > 1 ? dv : 0.f) + w.y;
        const float u2 = (c.z > 1 ? dv : 0.f) + w.z;
        const float u3 = (c.w > 1 ? dv : 0.f) + w.w;
        float s = (__expf(u0) + __expf(u1)) + (__expf(u2) + __expf(u3));
        float ub = 0.f;
        if (sub == (b2 >> 2)) {
            const int r = b2 & 3;
            ub = r == 0 ? u0 : r == 1 ? u1 : r == 2 ? u2 : u3;
        }
        s  += __shfl_xor(s, 1);  s  += __shfl_xor(s, 2);
        ub += __shfl_xor(ub, 1); ub += __shfl_xor(ub, 2);
        acc += ub - __logf(s) + LOG16f;
    }

    if (sub == 0) out[n] = acc;
}

extern "C" void kernel_launch(void* const* d_in, const int* in_sizes, int n_in,
                              void* d_out, int out_size, void* d_ws, size_t ws_size,
                              hipStream_t stream) {
    const int* bc0    = (const int*)d_in[0];
    const int* bc1    = (const int*)d_in[1];
    const int* bc2    = (const int*)d_in[2];
    const int* gix    = (const int*)d_in[3];
    const int* bixp   = (const int*)d_in[4];
    const int* labels = (const int*)d_in[5];
    const int* lci    = (const int*)d_in[6];
    const float* bw0  = (const float*)d_in[7];
    const float* dv0  = (const float*)d_in[8];
    const float* bw1  = (const float*)d_in[9];
    const float* dv1  = (const float*)d_in[10];
    const float* bw2  = (const float*)d_in[11];
    const float* dv2  = (const float*)d_in[12];
    float* out = (float*)d_out;

    const int N = in_sizes[6];  // local_cell_ix has N elements
    const long long totalThreads = 4LL * N;
    const int threads = 256;
    const int blocks = (int)((totalThreads + threads - 1) / threads);

    frag_pos_dist_kernel<<<blocks, threads, 0, stream>>>(
        bc0, bc1, bc2, gix, bixp, labels, lci,
        bw0, dv0, bw1, dv1, bw2, dv2, out, N);
}

// Round 4
// 99.111 us; speedup vs baseline: 2.7891x; 1.3536x over previous
//
#include <hip/hip_runtime.h>

#define LOG64f 4.1588830833596715f
#define LOG32f 3.4657359027997265f
#define LOG16f 2.7725887222397810f

// One wave = 16 consecutive fragments. Every bincount load is a fully
// contiguous 1KB wave transaction:
//   track0 (S=64): 16 lanes/fragment, 4 sub-iterations
//   track1 (S=32):  8 lanes/fragment, 2 sub-iterations
//   track2 (S=16):  4 lanes/fragment, 1 sub-iteration
// Segmented shfl_xor reductions; all vector loads issued up front into
// named registers for maximum MLP. No LDS, no barriers.

__device__ __forceinline__ void expsum4(const int4 c, const float4 w, const float dv,
                                        const int b, const int sub, float& s, float& ub)
{
    const float u0 = (c.x > 1 ? dv : 0.f) + w.x;
    const float u1 = (c.y > 1 ? dv : 0.f) + w.y;
    const float u2 = (c.z > 1 ? dv : 0.f) + w.z;
    const float u3 = (c.w > 1 ? dv : 0.f) + w.w;
    s  = (__expf(u0) + __expf(u1)) + (__expf(u2) + __expf(u3));
    ub = 0.f;
    if (sub == (b >> 2)) {
        const int r = b & 3;
        ub = r == 0 ? u0 : r == 1 ? u1 : r == 2 ? u2 : u3;
    }
}

__global__ __launch_bounds__(256) void frag_pos_dist_kernel(
    const int* __restrict__ bc0, const int* __restrict__ bc1, const int* __restrict__ bc2,
    const int* __restrict__ gix, const int* __restrict__ bix,
    const int* __restrict__ labels, const int* __restrict__ lci,
    const float* __restrict__ bw0, const float* __restrict__ d0,
    const float* __restrict__ bw1, const float* __restrict__ d1,
    const float* __restrict__ bw2, const float* __restrict__ d2,
    float* __restrict__ out, int N)
{
    const int lane = threadIdx.x & 63;
    const int wid  = blockIdx.x * (blockDim.x >> 6) + (threadIdx.x >> 6);
    const int base = wid * 16;
    if (base >= N) return;
    const int fl = lane & 15;      // fragment slot this lane owns (dup x4)

    // ---------- phase A: per-fragment scalars (lane fl <-> frag base+fl) ----
    int nf = base + fl; if (nf >= N) nf = N - 1;
    const int cell = lci[nf];
    const int lab  = labels[cell];
    const float dva = d0[lab], dvb = d1[lab], dvc = d2[lab];
    const int g0v = gix[3 * nf + 0], g1v = gix[3 * nf + 1], g2v = gix[3 * nf + 2];
    const int b0v = bix[3 * nf + 0], b1v = bix[3 * nf + 1], b2v = bix[3 * nf + 2];

    // ---------- phase B: broadcast per-iteration scalars ----------
    const int s16 = lane >> 4, s8 = lane >> 3, s4 = lane >> 2;
    const int f00 = s16, f01 = 4 + s16, f02 = 8 + s16, f03 = 12 + s16; // track0
    const int f10 = s8,  f11 = 8 + s8;                                  // track1
    const int f20 = s4;                                                  // track2

    const float dv00 = __shfl(dva, f00), dv01 = __shfl(dva, f01),
                dv02 = __shfl(dva, f02), dv03 = __shfl(dva, f03);
    const int   g00  = __shfl(g0v, f00), g01  = __shfl(g0v, f01),
                g02  = __shfl(g0v, f02), g03  = __shfl(g0v, f03);
    const int   b00  = __shfl(b0v, f00), b01  = __shfl(b0v, f01),
                b02  = __shfl(b0v, f02), b03  = __shfl(b0v, f03);

    const float dv10 = __shfl(dvb, f10), dv11 = __shfl(dvb, f11);
    const int   g10  = __shfl(g1v, f10), g11  = __shfl(g1v, f11);
    const int   b10  = __shfl(b1v, f10), b11  = __shfl(b1v, f11);

    const float dv20 = __shfl(dvc, f20);
    const int   g20  = __shfl(g2v, f20);
    const int   b20  = __shfl(b2v, f20);

    // ---------- phase C: issue ALL vector loads (contiguous 1KB/wave) -------
    int n00 = base + f00, n01 = base + f01, n02 = base + f02, n03 = base + f03;
    int n10 = base + f10, n11 = base + f11, n20 = base + f20;
    if (n00 >= N) n00 = N - 1;  if (n01 >= N) n01 = N - 1;
    if (n02 >= N) n02 = N - 1;  if (n03 >= N) n03 = N - 1;
    if (n10 >= N) n10 = N - 1;  if (n11 >= N) n11 = N - 1;
    if (n20 >= N) n20 = N - 1;

    const int sub0 = lane & 15, sub1 = lane & 7, sub2 = lane & 3;

    const int4 c00 = ((const int4*)(bc0 + (size_t)n00 * 64))[sub0];
    const int4 c01 = ((const int4*)(bc0 + (size_t)n01 * 64))[sub0];
    const int4 c02 = ((const int4*)(bc0 + (size_t)n02 * 64))[sub0];
    const int4 c03 = ((const int4*)(bc0 + (size_t)n03 * 64))[sub0];
    const int4 c10 = ((const int4*)(bc1 + (size_t)n10 * 32))[sub1];
    const int4 c11 = ((const int4*)(bc1 + (size_t)n11 * 32))[sub1];
    const int4 c20 = ((const int4*)(bc2 + (size_t)n20 * 16))[sub2];

    const float4 w00 = ((const float4*)(bw0 + (size_t)g00 * 64))[sub0];
    const float4 w01 = ((const float4*)(bw0 + (size_t)g01 * 64))[sub0];
    const float4 w02 = ((const float4*)(bw0 + (size_t)g02 * 64))[sub0];
    const float4 w03 = ((const float4*)(bw0 + (size_t)g03 * 64))[sub0];
    const float4 w10 = ((const float4*)(bw1 + (size_t)g10 * 32))[sub1];
    const float4 w11 = ((const float4*)(bw1 + (size_t)g11 * 32))[sub1];
    const float4 w20 = ((const float4*)(bw2 + (size_t)g20 * 16))[sub2];

    // ---------- phase D: compute ----------
    float acc = 0.0f;
    float s, ub, t, lp;

    // track 0: 16-lane segments, iterations j=0..3
    expsum4(c00, w00, dv00, b00, sub0, s, ub);
    s += __shfl_xor(s, 1); ub += __shfl_xor(ub, 1);
    s += __shfl_xor(s, 2); ub += __shfl_xor(ub, 2);
    s += __shfl_xor(s, 4); ub += __shfl_xor(ub, 4);
    s += __shfl_xor(s, 8); ub += __shfl_xor(ub, 8);
    lp = ub - __logf(s) + LOG64f;
    t = __shfl(lp, (fl & 3) << 4); if ((fl >> 2) == 0) acc += t;

    expsum4(c01, w01, dv01, b01, sub0, s, ub);
    s += __shfl_xor(s, 1); ub += __shfl_xor(ub, 1);
    s += __shfl_xor(s, 2); ub += __shfl_xor(ub, 2);
    s += __shfl_xor(s, 4); ub += __shfl_xor(ub, 4);
    s += __shfl_xor(s, 8); ub += __shfl_xor(ub, 8);
    lp = ub - __logf(s) + LOG64f;
    t = __shfl(lp, (fl & 3) << 4); if ((fl >> 2) == 1) acc += t;

    expsum4(c02, w02, dv02, b02, sub0, s, ub);
    s += __shfl_xor(s, 1); ub += __shfl_xor(ub, 1);
    s += __shfl_xor(s, 2); ub += __shfl_xor(ub, 2);
    s += __shfl_xor(s, 4); ub += __shfl_xor(ub, 4);
    s += __shfl_xor(s, 8); ub += __shfl_xor(ub, 8);
    lp = ub - __logf(s) + LOG64f;
    t = __shfl(lp, (fl & 3) << 4); if ((fl >> 2) == 2) acc += t;

    expsum4(c03, w03, dv03, b03, sub0, s, ub);
    s += __shfl_xor(s, 1); ub += __shfl_xor(ub, 1);
    s += __shfl_xor(s, 2); ub += __shfl_xor(ub, 2);
    s += __shfl_xor(s, 4); ub += __shfl_xor(ub, 4);
    s += __shfl_xor(s, 8); ub += __shfl_xor(ub, 8);
    lp = ub - __logf(s) + LOG64f;
    t = __shfl(lp, (fl & 3) << 4); if ((fl >> 2) == 3) acc += t;

    // track 1: 8-lane segments, iterations j=0..1
    expsum4(c10, w10, dv10, b10, sub1, s, ub);
    s += __shfl_xor(s, 1); ub += __shfl_xor(ub, 1);
    s += __shfl_xor(s, 2); ub += __shfl_xor(ub, 2);
    s += __shfl_xor(s, 4); ub += __shfl_xor(ub, 4);
    lp = ub - __logf(s) + LOG32f;
    t = __shfl(lp, (fl & 7) << 3); if ((fl >> 3) == 0) acc += t;

    expsum4(c11, w11, dv11, b11, sub1, s, ub);
    s += __shfl_xor(s, 1); ub += __shfl_xor(ub, 1);
    s += __shfl_xor(s, 2); ub += __shfl_xor(ub, 2);
    s += __shfl_xor(s, 4); ub += __shfl_xor(ub, 4);
    lp = ub - __logf(s) + LOG32f;
    t = __shfl(lp, (fl & 7) << 3); if ((fl >> 3) == 1) acc += t;

    // track 2: 4-lane segments, single iteration
    expsum4(c20, w20, dv20, b20, sub2, s, ub);
    s += __shfl_xor(s, 1); ub += __shfl_xor(ub, 1);
    s += __shfl_xor(s, 2); ub += __shfl_xor(ub, 2);
    lp = ub - __logf(s) + LOG16f;
    t = __shfl(lp, fl << 2); acc += t;

    // ---------- write: lanes 0..15 own fragments base..base+15 ----------
    if (lane < 16) {
        const int n = base + lane;
        if (n < N) out[n] = acc;
    }
}

extern "C" void kernel_launch(void* const* d_in, const int* in_sizes, int n_in,
                              void* d_out, int out_size, void* d_ws, size_t ws_size,
                              hipStream_t stream) {
    const int* bc0    = (const int*)d_in[0];
    const int* bc1    = (const int*)d_in[1];
    const int* bc2    = (const int*)d_in[2];
    const int* gix    = (const int*)d_in[3];
    const int* bixp   = (const int*)d_in[4];
    const int* labels = (const int*)d_in[5];
    const int* lci    = (const int*)d_in[6];
    const float* bw0  = (const float*)d_in[7];
    const float* dv0  = (const float*)d_in[8];
    const float* bw1  = (const float*)d_in[9];
    const float* dv1  = (const float*)d_in[10];
    const float* bw2  = (const float*)d_in[11];
    const float* dv2  = (const float*)d_in[12];
    float* out = (float*)d_out;

    const int N = in_sizes[6];  // local_cell_ix has N elements
    const int threads = 256;
    const int fragsPerBlock = 64;       // 4 waves * 16 fragments
    const int blocks = (N + fragsPerBlock - 1) / fragsPerBlock;

    frag_pos_dist_kernel<<<blocks, threads, 0, stream>>>(
        bc0, bc1, bc2, gix, bixp, labels, lci,
        bw0, dv0, bw1, dv1, bw2, dv2, out, N);
}